// Round 1
// baseline (542.335 us; speedup 1.0000x reference)
//
#include <hip/hip_runtime.h>
#include <math.h>

#define HW 65536
#define NCH 64
#define NB 4

// ---------------------------------------------------------------------------
// Table generation (recomputed every launch; ws is poisoned between calls).
// Mc[k][c] = cos(pi*k*(2c+1)/128)/64                      (channel DCT-II)
// Nc[m][v] = v==0 ? 1 : 2*cos(pi*v*(2m+1)/128)            (channel iDCT)
// At[w][k] = cos(pi*k*(2w+1)/512)/256                     (row DCT, transposed)
// Ah[kh][h] = cos(pi*kh*(2h+1)/512)/256                   (col DCT)
// ---------------------------------------------------------------------------
__global__ void gen_tables(float* __restrict__ Mc, float* __restrict__ Nc,
                           float* __restrict__ At, float* __restrict__ Ah) {
  int i = blockIdx.x * 256 + threadIdx.x;   // 0 .. 65535
  const double PI = 3.14159265358979323846;
  if (i < 4096) {
    int k = i >> 6, c = i & 63;
    Mc[i] = (float)(cos(PI * (double)(k * (2 * c + 1)) / 128.0) / 64.0);
    // Nc[m][v] with m=k, v=c
    Nc[i] = (c == 0) ? 1.0f
                     : (float)(2.0 * cos(PI * (double)(c * (2 * k + 1)) / 128.0));
  }
  {
    int r = i >> 8, c = i & 255;
    At[i] = (float)(cos(PI * (double)(c * (2 * r + 1)) / 512.0) / 256.0);
    Ah[i] = (float)(cos(PI * (double)(r * (2 * c + 1)) / 512.0) / 256.0);
  }
}

// ---------------------------------------------------------------------------
// Generic tiled fp32 GEMM: C[M x N] = A[M x K] * B[K x N], batched via strides.
// Block tile 64x64, 256 threads, 4x4 microtile, K-tile 16.
// Optional gate: B_eff[k][n] = B[k][n] * gate[n] (per batch).
// TOP8: skip C write; instead reduce block-tile top-8 -> top8out[blockIdx].
// All shapes used here divide the tiles exactly (no bounds checks).
// ---------------------------------------------------------------------------
template <bool TOP8>
__global__ __launch_bounds__(256) void gemm64(
    const float* __restrict__ Ag, int lda, long long sAb,
    const float* __restrict__ Bg, int ldb, long long sBb,
    float* __restrict__ Cg, int ldc, long long sCb, int K,
    const float* __restrict__ gate, long long sGb,
    float* __restrict__ top8out) {
  __shared__ float As[16][68];   // As[k][m], row stride 68 floats (16B aligned)
  __shared__ float Bs[16][68];   // Bs[k][n]
  const int tid = threadIdx.x;
  const int tx = tid & 15, ty = tid >> 4;
  const int bn = blockIdx.x, bm = blockIdx.y, bz = blockIdx.z;
  const float* Ab = Ag + bz * sAb + (long long)bm * 64 * lda;
  const float* Bp = Bg + bz * sBb;
  const long long n0 = (long long)bn * 64;
  const int bcol = tid & 63;   // B-tile column loaded by this thread
  const int brow = tid >> 6;   // 0..3
  const int acol = tid & 15;   // A-tile k-col loaded by this thread
  const int arow = tid >> 4;   // 0..15
  float g = 1.0f;
  if (gate) g = gate[bz * sGb + n0 + bcol];
  float acc[4][4] = {{0.f}};

  for (int k0 = 0; k0 < K; k0 += 16) {
#pragma unroll
    for (int i = 0; i < 4; i++) {   // A tile 64m x 16k -> transposed to As[k][m]
      int r = arow + 16 * i;
      As[acol][r] = Ab[(long long)r * lda + (k0 + acol)];
    }
#pragma unroll
    for (int i = 0; i < 4; i++) {   // B tile 16k x 64n
      int r = brow + 4 * i;
      Bs[r][bcol] = Bp[(long long)(k0 + r) * ldb + n0 + bcol] * g;
    }
    __syncthreads();
#pragma unroll
    for (int kk = 0; kk < 16; kk++) {
      float4 a4 = *(const float4*)&As[kk][ty * 4];
      float4 b4 = *(const float4*)&Bs[kk][tx * 4];
      float a[4] = {a4.x, a4.y, a4.z, a4.w};
      float b[4] = {b4.x, b4.y, b4.z, b4.w};
#pragma unroll
      for (int i = 0; i < 4; i++)
#pragma unroll
        for (int j = 0; j < 4; j++) acc[i][j] = fmaf(a[i], b[j], acc[i][j]);
    }
    __syncthreads();
  }

  if constexpr (!TOP8) {
#pragma unroll
    for (int i = 0; i < 4; i++) {
      float4 o;
      o.x = acc[i][0]; o.y = acc[i][1]; o.z = acc[i][2]; o.w = acc[i][3];
      *(float4*)&Cg[bz * sCb + (long long)(bm * 64 + ty * 4 + i) * ldc + n0 +
                    tx * 4] = o;
    }
  } else {
    __shared__ float lists[256 * 8];
    float t[8];
#pragma unroll
    for (int j = 0; j < 8; j++) t[j] = -INFINITY;
#pragma unroll
    for (int i = 0; i < 4; i++)
#pragma unroll
      for (int j = 0; j < 4; j++) {
        float v = acc[i][j];
#pragma unroll
        for (int q = 0; q < 8; q++) {
          if (v > t[q]) { float tmp = t[q]; t[q] = v; v = tmp; }
        }
      }
#pragma unroll
    for (int j = 0; j < 8; j++) lists[tid * 8 + j] = t[j];
    __syncthreads();
    for (int s = 128; s >= 1; s >>= 1) {   // merge 256 sorted-8 lists -> 1
      if (tid < s) {
        int ii = 0, jj = 0;
        float out[8];
#pragma unroll
        for (int m = 0; m < 8; m++) {
          float av = lists[tid * 8 + ii];
          float bv = lists[(tid + s) * 8 + jj];
          bool ta = (av >= bv);
          out[m] = ta ? av : bv;
          ii += ta ? 1 : 0;
          jj += ta ? 0 : 1;
        }
#pragma unroll
        for (int m = 0; m < 8; m++) lists[tid * 8 + m] = out[m];
      }
      __syncthreads();
    }
    if (tid < 8) {
      long long idx = ((long long)bz * gridDim.y + bm) * gridDim.x + bn;
      top8out[idx * 8 + tid] = lists[tid];
    }
  }
}

// ---------------------------------------------------------------------------
// Per-pixel top-8 over the 64 channel-DCT values (sorted descending).
// ---------------------------------------------------------------------------
__global__ __launch_bounds__(256) void top8_chan(const float* __restrict__ ca,
                                                 float* __restrict__ ct) {
  int gidx = blockIdx.x * 256 + threadIdx.x;   // b*HW + p
  int b = gidx >> 16, p = gidx & 65535;
  const float* src = ca + (long long)b * NCH * HW + p;
  float t[8];
#pragma unroll
  for (int j = 0; j < 8; j++) t[j] = -INFINITY;
  for (int c = 0; c < NCH; c++) {
    float v = src[(long long)c * HW];
#pragma unroll
    for (int q = 0; q < 8; q++) {
      if (v > t[q]) { float tmp = t[q]; t[q] = v; v = tmp; }
    }
  }
  float* dst = ct + (long long)b * 8 * HW + p;
#pragma unroll
  for (int j = 0; j < 8; j++) dst[(long long)j * HW] = t[j];
}

// ---------------------------------------------------------------------------
// 3x3 conv (8 in-ch -> 1) with SAME zero padding + sigmoid.
// ---------------------------------------------------------------------------
__global__ __launch_bounds__(256) void conv_gate(const float* __restrict__ ct,
                                                 const float* __restrict__ cw,
                                                 const float* __restrict__ cbias,
                                                 float* __restrict__ gate) {
  int gidx = blockIdx.x * 256 + threadIdx.x;
  int b = gidx >> 16, p = gidx & 65535;
  int h = p >> 8, w = p & 255;
  float acc = cbias[0];
#pragma unroll
  for (int j = 0; j < 8; j++) {
    const float* base = ct + ((long long)b * 8 + j) * HW;
#pragma unroll
    for (int dy = 0; dy < 3; dy++) {
      int y = h + dy - 1;
      if ((unsigned)y < 256u) {
#pragma unroll
        for (int dx = 0; dx < 3; dx++) {
          int x = w + dx - 1;
          if ((unsigned)x < 256u)
            acc += base[y * 256 + x] * cw[j * 9 + dy * 3 + dx];
        }
      }
    }
  }
  gate[gidx] = 1.0f / (1.0f + expf(-acc));
}

// ---------------------------------------------------------------------------
// Merge the 16 per-tile top-8 lists of each image -> topc[b*512 + c*8 + j].
// ---------------------------------------------------------------------------
__global__ void merge_top8(const float* __restrict__ lists,
                           float* __restrict__ topc) {
  int img = blockIdx.x * 64 + threadIdx.x;   // b*64 + c
  if (img >= 256) return;
  float t[8];
#pragma unroll
  for (int j = 0; j < 8; j++) t[j] = -INFINITY;
  for (int l = 0; l < 16; l++) {
#pragma unroll
    for (int m = 0; m < 8; m++) {
      float v = lists[(img * 16 + l) * 8 + m];
#pragma unroll
      for (int q = 0; q < 8; q++) {
        if (v > t[q]) { float tmp = t[q]; t[q] = v; v = tmp; }
      }
    }
  }
  int b = img >> 6, c = img & 63;
#pragma unroll
  for (int j = 0; j < 8; j++) topc[b * 512 + c * 8 + j] = t[j];
}

// ---------------------------------------------------------------------------
// MLP: h = relu(topc @ fc1^T)  [4x8];  w = sigmoid(h @ fc2^T)  [4x64].
// ---------------------------------------------------------------------------
__global__ void mlp_kernel(const float* __restrict__ topc,
                           const float* __restrict__ fc1,
                           const float* __restrict__ fc2,
                           float* __restrict__ wout) {
  __shared__ float hbuf[32];
  int tid = threadIdx.x;
  if (tid < 32) {
    int b = tid >> 3, i = tid & 7;
    float acc = 0.f;
    for (int j = 0; j < 512; j++) acc += topc[b * 512 + j] * fc1[i * 512 + j];
    hbuf[tid] = fmaxf(acc, 0.f);
  }
  __syncthreads();
  int b = tid >> 6, c = tid & 63;
  float acc = 0.f;
#pragma unroll
  for (int i = 0; i < 8; i++) acc += hbuf[b * 8 + i] * fc2[c * 8 + i];
  wout[tid] = 1.0f / (1.0f + expf(-acc));
}

// ---------------------------------------------------------------------------
// out[b,c,p] *= w[b,c]  (in place on d_out, float4).
// ---------------------------------------------------------------------------
__global__ __launch_bounds__(256) void scale_out(float* __restrict__ out,
                                                 const float* __restrict__ wout) {
  long long i = ((long long)blockIdx.x * 256 + threadIdx.x) * 4;
  float4 v = *(float4*)&out[i];
  float s = wout[(int)(i >> 16)];
  v.x *= s; v.y *= s; v.z *= s; v.w *= s;
  *(float4*)&out[i] = v;
}

// ---------------------------------------------------------------------------
extern "C" void kernel_launch(void* const* d_in, const int* in_sizes, int n_in,
                              void* d_out, int out_size, void* d_ws,
                              size_t ws_size, hipStream_t stream) {
  (void)in_sizes; (void)n_in; (void)out_size; (void)ws_size;
  const float* ip  = (const float*)d_in[0];
  const float* fc1 = (const float*)d_in[1];
  const float* fc2 = (const float*)d_in[2];
  const float* cw  = (const float*)d_in[3];
  const float* cb  = (const float*)d_in[4];
  float* out = (float*)d_out;
  float* ws = (float*)d_ws;

  // ws layout (floats). Total = 19,922,944 floats ~= 76 MiB.
  float* Mc     = ws;                       //   4096
  float* Nc     = ws + 4096;                //   4096
  float* At     = ws + 8192;                //  65536
  float* Ah     = ws + 73728;               //  65536
  float* gateb  = ws + 139264;              // 262144
  float* wfin   = ws + 401408;              //    256
  float* topc   = ws + 401664;              //   2048
  float* listsb = ws + 403712;              //  32768 (256 imgs * 16 tiles * 8)
  float* ca     = ws + 1048576;             // 16777216 (ca; reused as R later)
  float* ct8    = ws + 1048576 + 16777216;  //  2097152 (channel top-8)

  const long long CHW = (long long)NCH * HW;

  gen_tables<<<256, 256, 0, stream>>>(Mc, Nc, At, Ah);

  // ca = Mc @ ip   (batched over B;  M=64, N=HW, K=64)
  gemm64<false><<<dim3(1024, 1, 4), 256, 0, stream>>>(
      Mc, 64, 0, ip, HW, CHW, ca, HW, CHW, 64, nullptr, 0, nullptr);

  top8_chan<<<1024, 256, 0, stream>>>(ca, ct8);
  conv_gate<<<1024, 256, 0, stream>>>(ct8, cw, cb, gateb);

  // x = Nc @ (ca * gate)  -> d_out   (M=64, N=HW, K=64, gate fused on B-cols)
  gemm64<false><<<dim3(1024, 1, 4), 256, 0, stream>>>(
      Nc, 64, 0, ca, HW, CHW, out, HW, CHW, 64, gateb, HW, nullptr);

  // R = x @ At   (M=B*C*H=65536, N=256, K=256) -> reuse ca buffer
  float* R = ca;
  gemm64<false><<<dim3(4, 1024, 1), 256, 0, stream>>>(
      out, 256, 0, At, 256, 0, R, 256, 0, 256, nullptr, 0, nullptr);

  // D = Ah @ R per image, fused top-8 per 64x64 tile (D never materialized)
  gemm64<true><<<dim3(4, 4, 256), 256, 0, stream>>>(
      Ah, 256, 0, R, 256, 65536, nullptr, 0, 0, 256, nullptr, 0, listsb);

  merge_top8<<<4, 64, 0, stream>>>(listsb, topc);
  mlp_kernel<<<1, 256, 0, stream>>>(topc, fc1, fc2, wfin);
  scale_out<<<16384, 256, 0, stream>>>(out, wfin);
}

// Round 2
// 320.960 us; speedup vs baseline: 1.6897x; 1.6897x over previous
//
#include <hip/hip_runtime.h>
#include <hip/hip_bf16.h>
#include <math.h>

#define HW 65536
#define NCH 64
#define NB 4

typedef __attribute__((ext_vector_type(8))) short bf16x8;
typedef __attribute__((ext_vector_type(4))) float f32x4;
typedef __attribute__((ext_vector_type(8))) unsigned short u16x8;

__device__ inline unsigned short f2b(float f) {
  __hip_bfloat16 h = __float2bfloat16(f);
  return *(unsigned short*)&h;
}

// ---------------------------------------------------------------------------
// Tables (recomputed every launch; ws is poisoned between calls).
// Mc[k][c] = cos(pi*k*(2c+1)/128)/64              (channel DCT-II)
// Nc[m][v] = v==0 ? 1 : 2*cos(pi*v*(2m+1)/128)    (channel iDCT)
// Tb[n][k] = bf16(cos(pi*n*(2k+1)/512)/256)       (spatial DCT, shared by
//            row-DCT as B^T and col-DCT as A)
// ---------------------------------------------------------------------------
__global__ void gen_tables(float* __restrict__ Mc, float* __restrict__ Nc,
                           unsigned short* __restrict__ Tb) {
  int i = blockIdx.x * 256 + threadIdx.x;   // 0 .. 65535
  const double PI = 3.14159265358979323846;
  if (i < 4096) {
    int k = i >> 6, c = i & 63;
    Mc[i] = (float)(cos(PI * (double)(k * (2 * c + 1)) / 128.0) / 64.0);
    Nc[i] = (c == 0) ? 1.0f
                     : (float)(2.0 * cos(PI * (double)(c * (2 * k + 1)) / 128.0));
  }
  {
    int n = i >> 8, k = i & 255;
    float v = (float)(cos(PI * (double)(n * (2 * k + 1)) / 512.0) / 256.0);
    Tb[i] = f2b(v);
  }
}

// ---------------------------------------------------------------------------
// Tiled fp32 GEMM (channel path only): C = A[MxK] * B[KxN], batched strides.
// 64x64 block tile, 256 threads, 4x4 microtile, K-tile 16.
// gate: B_eff[k][n] = B[k][n] * gate[n] (per batch).
// ---------------------------------------------------------------------------
__global__ __launch_bounds__(256) void gemm64(
    const float* __restrict__ Ag, int lda, long long sAb,
    const float* __restrict__ Bg, int ldb, long long sBb,
    float* __restrict__ Cg, int ldc, long long sCb, int K,
    const float* __restrict__ gate, long long sGb) {
  __shared__ float As[16][68];
  __shared__ float Bs[16][68];
  const int tid = threadIdx.x;
  const int tx = tid & 15, ty = tid >> 4;
  const int bn = blockIdx.x, bm = blockIdx.y, bz = blockIdx.z;
  const float* Ab = Ag + bz * sAb + (long long)bm * 64 * lda;
  const float* Bp = Bg + bz * sBb;
  const long long n0 = (long long)bn * 64;
  const int bcol = tid & 63;
  const int brow = tid >> 6;
  const int acol = tid & 15;
  const int arow = tid >> 4;
  float g = 1.0f;
  if (gate) g = gate[bz * sGb + n0 + bcol];
  float acc[4][4] = {{0.f}};

  for (int k0 = 0; k0 < K; k0 += 16) {
#pragma unroll
    for (int i = 0; i < 4; i++) {
      int r = arow + 16 * i;
      As[acol][r] = Ab[(long long)r * lda + (k0 + acol)];
    }
#pragma unroll
    for (int i = 0; i < 4; i++) {
      int r = brow + 4 * i;
      Bs[r][bcol] = Bp[(long long)(k0 + r) * ldb + n0 + bcol] * g;
    }
    __syncthreads();
#pragma unroll
    for (int kk = 0; kk < 16; kk++) {
      float4 a4 = *(const float4*)&As[kk][ty * 4];
      float4 b4 = *(const float4*)&Bs[kk][tx * 4];
      float a[4] = {a4.x, a4.y, a4.z, a4.w};
      float b[4] = {b4.x, b4.y, b4.z, b4.w};
#pragma unroll
      for (int i = 0; i < 4; i++)
#pragma unroll
        for (int j = 0; j < 4; j++) acc[i][j] = fmaf(a[i], b[j], acc[i][j]);
    }
    __syncthreads();
  }
#pragma unroll
  for (int i = 0; i < 4; i++) {
    float4 o;
    o.x = acc[i][0]; o.y = acc[i][1]; o.z = acc[i][2]; o.w = acc[i][3];
    *(float4*)&Cg[bz * sCb + (long long)(bm * 64 + ty * 4 + i) * ldc + n0 +
                  tx * 4] = o;
  }
}

// ---------------------------------------------------------------------------
// MFMA row-DCT: Rt[img][n][h] = sum_k x[(img,h)][k] * Tb[n][k]  (bf16 in/out,
// fp32 accum). x = [65536 x 256] fp32; Rt stored TRANSPOSED per image so the
// col-DCT kernel stages linearly. Block tile 128(m) x 128(n), 4 waves, BK=32.
// ---------------------------------------------------------------------------
__global__ __launch_bounds__(256) void mfma_rowdct(
    const float* __restrict__ x, const unsigned short* __restrict__ Tb,
    unsigned short* __restrict__ Rt) {
  __shared__ unsigned short As[128][40];   // As[m][k], pad->80B rows
  __shared__ unsigned short Bs[128][40];   // Bs[n][k] = Tb slice
  const int tid = threadIdx.x;
  const int m0 = blockIdx.y * 128;         // global row (img*256 + h)
  const int n0 = blockIdx.x * 128;         // wfreq
  const int wv = tid >> 6, lane = tid & 63;
  const int wr = wv >> 1, wc = wv & 1;
  const int l15 = lane & 15, kb = lane >> 4;
  const int srow = tid & 127, sseg = tid >> 7;   // staging: row, 8-col segment
  f32x4 acc[4][4] = {};

  for (int k0 = 0; k0 < 256; k0 += 32) {
    {  // A: fp32 -> bf16
      const float* p = x + (long long)(m0 + srow) * 256 + k0 + sseg * 8;
      float4 v0 = *(const float4*)p;
      float4 v1 = *(const float4*)(p + 4);
      u16x8 w;
      w[0] = f2b(v0.x); w[1] = f2b(v0.y); w[2] = f2b(v0.z); w[3] = f2b(v0.w);
      w[4] = f2b(v1.x); w[5] = f2b(v1.y); w[6] = f2b(v1.z); w[7] = f2b(v1.w);
      *(u16x8*)&As[srow][sseg * 8] = w;
    }
    *(u16x8*)&Bs[srow][sseg * 8] =
        *(const u16x8*)(Tb + (n0 + srow) * 256 + k0 + sseg * 8);
    __syncthreads();
    bf16x8 a[4], b[4];
#pragma unroll
    for (int mi = 0; mi < 4; mi++)
      a[mi] = *(const bf16x8*)&As[wr * 64 + mi * 16 + l15][kb * 8];
#pragma unroll
    for (int ni = 0; ni < 4; ni++)
      b[ni] = *(const bf16x8*)&Bs[wc * 64 + ni * 16 + l15][kb * 8];
#pragma unroll
    for (int mi = 0; mi < 4; mi++)
#pragma unroll
      for (int ni = 0; ni < 4; ni++)
        acc[mi][ni] = __builtin_amdgcn_mfma_f32_16x16x32_bf16(
            a[mi], b[ni], acc[mi][ni], 0, 0, 0);
    __syncthreads();
  }

  const int img = m0 >> 8;                 // uniform per block
  const int hb = (m0 & 255) + wr * 64 + kb * 4;
#pragma unroll
  for (int mi = 0; mi < 4; mi++) {
#pragma unroll
    for (int ni = 0; ni < 4; ni++) {
      int h = hb + mi * 16;
      int n = n0 + wc * 64 + ni * 16 + l15;
      ushort4 o;
      o.x = f2b(acc[mi][ni][0]); o.y = f2b(acc[mi][ni][1]);
      o.z = f2b(acc[mi][ni][2]); o.w = f2b(acc[mi][ni][3]);
      *(ushort4*)&Rt[(long long)img * 65536 + (long long)n * 256 + h] = o;
    }
  }
}

// ---------------------------------------------------------------------------
// MFMA col-DCT + fused top-8: D_img = Tb(A) @ R_img, tile 128x128 per block,
// grid (2 n, 2 m, 256 img). D never materialized; per-block sorted top-8 out.
// ---------------------------------------------------------------------------
__global__ __launch_bounds__(256) void mfma_coldct_top8(
    const unsigned short* __restrict__ Tb, const unsigned short* __restrict__ Rt,
    float* __restrict__ top8out) {
  __shared__ unsigned short As[128][40];
  __shared__ unsigned short Bs[128][40];
  __shared__ float lists[256 * 8];
  const int tid = threadIdx.x;
  const int m0 = blockIdx.y * 128;         // kh
  const int n0 = blockIdx.x * 128;         // wfreq
  const int img = blockIdx.z;
  const int wv = tid >> 6, lane = tid & 63;
  const int wr = wv >> 1, wc = wv & 1;
  const int l15 = lane & 15, kb = lane >> 4;
  const int srow = tid & 127, sseg = tid >> 7;
  const unsigned short* Rb = Rt + (long long)img * 65536;
  f32x4 acc[4][4] = {};

  for (int k0 = 0; k0 < 256; k0 += 32) {
    *(u16x8*)&As[srow][sseg * 8] =
        *(const u16x8*)(Tb + (m0 + srow) * 256 + k0 + sseg * 8);
    *(u16x8*)&Bs[srow][sseg * 8] =
        *(const u16x8*)(Rb + (n0 + srow) * 256 + k0 + sseg * 8);
    __syncthreads();
    bf16x8 a[4], b[4];
#pragma unroll
    for (int mi = 0; mi < 4; mi++)
      a[mi] = *(const bf16x8*)&As[wr * 64 + mi * 16 + l15][kb * 8];
#pragma unroll
    for (int ni = 0; ni < 4; ni++)
      b[ni] = *(const bf16x8*)&Bs[wc * 64 + ni * 16 + l15][kb * 8];
#pragma unroll
    for (int mi = 0; mi < 4; mi++)
#pragma unroll
      for (int ni = 0; ni < 4; ni++)
        acc[mi][ni] = __builtin_amdgcn_mfma_f32_16x16x32_bf16(
            a[mi], b[ni], acc[mi][ni], 0, 0, 0);
    __syncthreads();
  }

  float t[8];
#pragma unroll
  for (int j = 0; j < 8; j++) t[j] = -INFINITY;
#pragma unroll
  for (int mi = 0; mi < 4; mi++)
#pragma unroll
    for (int ni = 0; ni < 4; ni++)
#pragma unroll
      for (int j = 0; j < 4; j++) {
        float v = acc[mi][ni][j];
#pragma unroll
        for (int q = 0; q < 8; q++) {
          if (v > t[q]) { float tmp = t[q]; t[q] = v; v = tmp; }
        }
      }
#pragma unroll
  for (int j = 0; j < 8; j++) lists[tid * 8 + j] = t[j];
  __syncthreads();
  for (int s = 128; s >= 1; s >>= 1) {
    if (tid < s) {
      int ii = 0, jj = 0;
      float out[8];
#pragma unroll
      for (int m = 0; m < 8; m++) {
        float av = lists[tid * 8 + ii];
        float bv = lists[(tid + s) * 8 + jj];
        bool ta = (av >= bv);
        out[m] = ta ? av : bv;
        ii += ta ? 1 : 0;
        jj += ta ? 0 : 1;
      }
#pragma unroll
      for (int m = 0; m < 8; m++) lists[tid * 8 + m] = out[m];
    }
    __syncthreads();
  }
  if (tid < 8) {
    long long idx = ((long long)img * gridDim.y + blockIdx.y) * gridDim.x +
                    blockIdx.x;
    top8out[idx * 8 + tid] = lists[tid];
  }
}

// ---------------------------------------------------------------------------
__global__ __launch_bounds__(256) void top8_chan(const float* __restrict__ ca,
                                                 float* __restrict__ ct) {
  int gidx = blockIdx.x * 256 + threadIdx.x;
  int b = gidx >> 16, p = gidx & 65535;
  const float* src = ca + (long long)b * NCH * HW + p;
  float t[8];
#pragma unroll
  for (int j = 0; j < 8; j++) t[j] = -INFINITY;
  for (int c = 0; c < NCH; c++) {
    float v = src[(long long)c * HW];
#pragma unroll
    for (int q = 0; q < 8; q++) {
      if (v > t[q]) { float tmp = t[q]; t[q] = v; v = tmp; }
    }
  }
  float* dst = ct + (long long)b * 8 * HW + p;
#pragma unroll
  for (int j = 0; j < 8; j++) dst[(long long)j * HW] = t[j];
}

__global__ __launch_bounds__(256) void conv_gate(const float* __restrict__ ct,
                                                 const float* __restrict__ cw,
                                                 const float* __restrict__ cbias,
                                                 float* __restrict__ gate) {
  int gidx = blockIdx.x * 256 + threadIdx.x;
  int b = gidx >> 16, p = gidx & 65535;
  int h = p >> 8, w = p & 255;
  float acc = cbias[0];
#pragma unroll
  for (int j = 0; j < 8; j++) {
    const float* base = ct + ((long long)b * 8 + j) * HW;
#pragma unroll
    for (int dy = 0; dy < 3; dy++) {
      int y = h + dy - 1;
      if ((unsigned)y < 256u) {
#pragma unroll
        for (int dx = 0; dx < 3; dx++) {
          int x = w + dx - 1;
          if ((unsigned)x < 256u)
            acc += base[y * 256 + x] * cw[j * 9 + dy * 3 + dx];
        }
      }
    }
  }
  gate[gidx] = 1.0f / (1.0f + expf(-acc));
}

// Merge the 4 per-tile top-8 lists of each image -> topc[b*512 + c*8 + j].
__global__ void merge_top8(const float* __restrict__ lists,
                           float* __restrict__ topc) {
  int img = blockIdx.x * 64 + threadIdx.x;
  if (img >= 256) return;
  float t[8];
#pragma unroll
  for (int j = 0; j < 8; j++) t[j] = -INFINITY;
  for (int l = 0; l < 4; l++) {
#pragma unroll
    for (int m = 0; m < 8; m++) {
      float v = lists[(img * 4 + l) * 8 + m];
#pragma unroll
      for (int q = 0; q < 8; q++) {
        if (v > t[q]) { float tmp = t[q]; t[q] = v; v = tmp; }
      }
    }
  }
  int b = img >> 6, c = img & 63;
#pragma unroll
  for (int j = 0; j < 8; j++) topc[b * 512 + c * 8 + j] = t[j];
}

__global__ void mlp_kernel(const float* __restrict__ topc,
                           const float* __restrict__ fc1,
                           const float* __restrict__ fc2,
                           float* __restrict__ wout) {
  __shared__ float hbuf[32];
  int tid = threadIdx.x;
  if (tid < 32) {
    int b = tid >> 3, i = tid & 7;
    float acc = 0.f;
    for (int j = 0; j < 512; j++) acc += topc[b * 512 + j] * fc1[i * 512 + j];
    hbuf[tid] = fmaxf(acc, 0.f);
  }
  __syncthreads();
  int b = tid >> 6, c = tid & 63;
  float acc = 0.f;
#pragma unroll
  for (int i = 0; i < 8; i++) acc += hbuf[b * 8 + i] * fc2[c * 8 + i];
  wout[tid] = 1.0f / (1.0f + expf(-acc));
}

__global__ __launch_bounds__(256) void scale_out(float* __restrict__ out,
                                                 const float* __restrict__ wout) {
  long long i = ((long long)blockIdx.x * 256 + threadIdx.x) * 4;
  float4 v = *(float4*)&out[i];
  float s = wout[(int)(i >> 16)];
  v.x *= s; v.y *= s; v.z *= s; v.w *= s;
  *(float4*)&out[i] = v;
}

// ---------------------------------------------------------------------------
extern "C" void kernel_launch(void* const* d_in, const int* in_sizes, int n_in,
                              void* d_out, int out_size, void* d_ws,
                              size_t ws_size, hipStream_t stream) {
  (void)in_sizes; (void)n_in; (void)out_size; (void)ws_size;
  const float* ip  = (const float*)d_in[0];
  const float* fc1 = (const float*)d_in[1];
  const float* fc2 = (const float*)d_in[2];
  const float* cw  = (const float*)d_in[3];
  const float* cb  = (const float*)d_in[4];
  float* out = (float*)d_out;
  float* ws = (float*)d_ws;

  // ws layout (floats).
  float* Mc     = ws;                       //   4096
  float* Nc     = ws + 4096;                //   4096
  unsigned short* Tb = (unsigned short*)(ws + 8192);   // 65536 u16 (32768 fl)
  float* gateb  = ws + 139264;              // 262144
  float* wfin   = ws + 401408;              //    256
  float* topc   = ws + 401664;              //   2048
  float* listsb = ws + 403712;              //   8192 (256 imgs * 4 tiles * 8)
  float* ca     = ws + 1048576;             // 16777216 (ca; Rt reuses later)
  float* ct8    = ws + 1048576 + 16777216;  //  2097152 (channel top-8)

  const long long CHW = (long long)NCH * HW;

  gen_tables<<<256, 256, 0, stream>>>(Mc, Nc, Tb);

  // ca = Mc @ ip   (batched over B;  M=64, N=HW, K=64)
  gemm64<<<dim3(1024, 1, 4), 256, 0, stream>>>(
      Mc, 64, 0, ip, HW, CHW, ca, HW, CHW, 64, nullptr, 0);

  top8_chan<<<1024, 256, 0, stream>>>(ca, ct8);
  conv_gate<<<1024, 256, 0, stream>>>(ct8, cw, cb, gateb);

  // x = Nc @ (ca * gate)  -> d_out
  gemm64<<<dim3(1024, 1, 4), 256, 0, stream>>>(
      Nc, 64, 0, ca, HW, CHW, out, HW, CHW, 64, gateb, HW);

  // Rt[img][wfreq][h] = row-DCT of x, transposed per image (bf16)
  unsigned short* Rt = (unsigned short*)ca;
  mfma_rowdct<<<dim3(2, 512), 256, 0, stream>>>(out, Tb, Rt);

  // col-DCT + fused top-8 (D never materialized)
  mfma_coldct_top8<<<dim3(2, 2, 256), 256, 0, stream>>>(Tb, Rt, listsb);

  merge_top8<<<4, 64, 0, stream>>>(listsb, topc);
  mlp_kernel<<<1, 256, 0, stream>>>(topc, fc1, fc2, wfin);
  scale_out<<<16384, 256, 0, stream>>>(out, wfin);
}

// Round 6
// 296.497 us; speedup vs baseline: 1.8291x; 1.0825x over previous
//
#include <hip/hip_runtime.h>
#include <hip/hip_bf16.h>
#include <math.h>

#define HW 65536
#define NCH 64
#define NB 4

typedef __attribute__((ext_vector_type(8))) short bf16x8;
typedef __attribute__((ext_vector_type(4))) float f32x4;
typedef __attribute__((ext_vector_type(8))) unsigned short u16x8;

__device__ inline unsigned short f2b(float f) {
  __hip_bfloat16 h = __float2bfloat16(f);
  return *(unsigned short*)&h;
}

// ---------------------------------------------------------------------------
// Tables. Mc[k][c] = cos(pi*k*(2c+1)/128)/64 (channel DCT-II, fp32).
// Tb[n][k] = bf16(cos(pi*n*(2k+1)/512)/256)  (spatial DCT table).
// x = idct_chan(dct_chan(ip)*g) == ip*g exactly (gate channel-constant,
// idct linear + inverse of dct) -- validated by R2's explicit roundtrip.
// ---------------------------------------------------------------------------
__global__ void gen_tables(float* __restrict__ Mc,
                           unsigned short* __restrict__ Tb) {
  int i = blockIdx.x * 256 + threadIdx.x;   // 0 .. 65535
  const double PI = 3.14159265358979323846;
  if (i < 4096) {
    int k = i >> 6, c = i & 63;
    Mc[i] = (float)(cos(PI * (double)(k * (2 * c + 1)) / 128.0) / 64.0);
  }
  {
    int n = i >> 8, k = i & 255;
    float v = (float)(cos(PI * (double)(n * (2 * k + 1)) / 512.0) / 256.0);
    Tb[i] = f2b(v);
  }
}

// ---------------------------------------------------------------------------
// Tiled fp32 GEMM (R2-proven): C = A[MxK] * B[KxN], batched strides.
// 64x64 block tile, 256 threads, 4x4 microtile, K-tile 16.
// ---------------------------------------------------------------------------
__global__ __launch_bounds__(256) void gemm64(
    const float* __restrict__ Ag, int lda, long long sAb,
    const float* __restrict__ Bg, int ldb, long long sBb,
    float* __restrict__ Cg, int ldc, long long sCb, int K,
    const float* __restrict__ gate, long long sGb) {
  __shared__ float As[16][68];
  __shared__ float Bs[16][68];
  const int tid = threadIdx.x;
  const int tx = tid & 15, ty = tid >> 4;
  const int bn = blockIdx.x, bm = blockIdx.y, bz = blockIdx.z;
  const float* Ab = Ag + bz * sAb + (long long)bm * 64 * lda;
  const float* Bp = Bg + bz * sBb;
  const long long n0 = (long long)bn * 64;
  const int bcol = tid & 63;
  const int brow = tid >> 6;
  const int acol = tid & 15;
  const int arow = tid >> 4;
  float g = 1.0f;
  if (gate) g = gate[bz * sGb + n0 + bcol];
  float acc[4][4] = {{0.f}};

  for (int k0 = 0; k0 < K; k0 += 16) {
#pragma unroll
    for (int i = 0; i < 4; i++) {
      int r = arow + 16 * i;
      As[acol][r] = Ab[(long long)r * lda + (k0 + acol)];
    }
#pragma unroll
    for (int i = 0; i < 4; i++) {
      int r = brow + 4 * i;
      Bs[r][bcol] = Bp[(long long)(k0 + r) * ldb + n0 + bcol] * g;
    }
    __syncthreads();
#pragma unroll
    for (int kk = 0; kk < 16; kk++) {
      float4 a4 = *(const float4*)&As[kk][ty * 4];
      float4 b4 = *(const float4*)&Bs[kk][tx * 4];
      float a[4] = {a4.x, a4.y, a4.z, a4.w};
      float b[4] = {b4.x, b4.y, b4.z, b4.w};
#pragma unroll
      for (int i = 0; i < 4; i++)
#pragma unroll
        for (int j = 0; j < 4; j++) acc[i][j] = fmaf(a[i], b[j], acc[i][j]);
    }
    __syncthreads();
  }
#pragma unroll
  for (int i = 0; i < 4; i++) {
    float4 o;
    o.x = acc[i][0]; o.y = acc[i][1]; o.z = acc[i][2]; o.w = acc[i][3];
    *(float4*)&Cg[bz * sCb + (long long)(bm * 64 + ty * 4 + i) * ldc + n0 +
                  tx * 4] = o;
  }
}

// ---------------------------------------------------------------------------
// Per-pixel top-8 over the 64 channel-DCT values (R2-proven).
// ---------------------------------------------------------------------------
__global__ __launch_bounds__(256) void top8_chan(const float* __restrict__ ca,
                                                 float* __restrict__ ct) {
  int gidx = blockIdx.x * 256 + threadIdx.x;
  int b = gidx >> 16, p = gidx & 65535;
  const float* src = ca + (long long)b * NCH * HW + p;
  float t[8];
#pragma unroll
  for (int j = 0; j < 8; j++) t[j] = -INFINITY;
  for (int c = 0; c < NCH; c++) {
    float v = src[(long long)c * HW];
#pragma unroll
    for (int q = 0; q < 8; q++) {
      if (v > t[q]) { float tmp = t[q]; t[q] = v; v = tmp; }
    }
  }
  float* dst = ct + (long long)b * 8 * HW + p;
#pragma unroll
  for (int j = 0; j < 8; j++) dst[(long long)j * HW] = t[j];
}

// ---------------------------------------------------------------------------
// 3x3 conv (8 in-ch -> 1) SAME + sigmoid -> gate (R2-proven).
// ---------------------------------------------------------------------------
__global__ __launch_bounds__(256) void conv_gate(const float* __restrict__ ct,
                                                 const float* __restrict__ cw,
                                                 const float* __restrict__ cbias,
                                                 float* __restrict__ gate) {
  int gidx = blockIdx.x * 256 + threadIdx.x;
  int b = gidx >> 16, p = gidx & 65535;
  int h = p >> 8, w = p & 255;
  float acc = cbias[0];
#pragma unroll
  for (int j = 0; j < 8; j++) {
    const float* base = ct + ((long long)b * 8 + j) * HW;
#pragma unroll
    for (int dy = 0; dy < 3; dy++) {
      int y = h + dy - 1;
      if ((unsigned)y < 256u) {
#pragma unroll
        for (int dx = 0; dx < 3; dx++) {
          int x = w + dx - 1;
          if ((unsigned)x < 256u)
            acc += base[y * 256 + x] * cw[j * 9 + dy * 3 + dx];
        }
      }
    }
  }
  gate[gidx] = 1.0f / (1.0f + expf(-acc));
}

// ---------------------------------------------------------------------------
// MFMA row-DCT with x = ip*gate computed on the fly (UNDER TEST).
// Rt[img][n][h] = sum_w x[(img,h)][w] * Tb[n][w], transposed per image.
// ---------------------------------------------------------------------------
__global__ __launch_bounds__(256) void mfma_rowdct(
    const float* __restrict__ ip, const float* __restrict__ gateb,
    const unsigned short* __restrict__ Tb, unsigned short* __restrict__ Rt) {
  __shared__ unsigned short As[128][40];
  __shared__ unsigned short Bs[128][40];
  const int tid = threadIdx.x;
  const int m0 = blockIdx.y * 128;         // global row (b*64+c)*256 + h
  const int n0 = blockIdx.x * 128;         // wfreq
  const int wv = tid >> 6, lane = tid & 63;
  const int wr = wv >> 1, wc = wv & 1;
  const int l15 = lane & 15, kb = lane >> 4;
  const int srow = tid & 127, sseg = tid >> 7;
  f32x4 acc[4][4] = {};

  for (int k0 = 0; k0 < 256; k0 += 32) {
    {  // A: x = ip*gate -> bf16
      const int r = m0 + srow;
      const int h = r & 255;
      const int b = r >> 14;
      const float* p  = ip + (long long)r * 256 + k0 + sseg * 8;
      const float* gp = gateb + ((long long)b << 16) + (h << 8) + k0 + sseg * 8;
      float4 v0 = *(const float4*)p,  v1 = *(const float4*)(p + 4);
      float4 g0 = *(const float4*)gp, g1 = *(const float4*)(gp + 4);
      u16x8 w;
      w[0] = f2b(v0.x * g0.x); w[1] = f2b(v0.y * g0.y);
      w[2] = f2b(v0.z * g0.z); w[3] = f2b(v0.w * g0.w);
      w[4] = f2b(v1.x * g1.x); w[5] = f2b(v1.y * g1.y);
      w[6] = f2b(v1.z * g1.z); w[7] = f2b(v1.w * g1.w);
      *(u16x8*)&As[srow][sseg * 8] = w;
    }
    *(u16x8*)&Bs[srow][sseg * 8] =
        *(const u16x8*)(Tb + (n0 + srow) * 256 + k0 + sseg * 8);
    __syncthreads();
    bf16x8 a[4], b[4];
#pragma unroll
    for (int mi = 0; mi < 4; mi++)
      a[mi] = *(const bf16x8*)&As[wr * 64 + mi * 16 + l15][kb * 8];
#pragma unroll
    for (int ni = 0; ni < 4; ni++)
      b[ni] = *(const bf16x8*)&Bs[wc * 64 + ni * 16 + l15][kb * 8];
#pragma unroll
    for (int mi = 0; mi < 4; mi++)
#pragma unroll
      for (int ni = 0; ni < 4; ni++)
        acc[mi][ni] = __builtin_amdgcn_mfma_f32_16x16x32_bf16(
            a[mi], b[ni], acc[mi][ni], 0, 0, 0);
    __syncthreads();
  }

  const int img = m0 >> 8;
  const int hb = (m0 & 255) + wr * 64 + kb * 4;
#pragma unroll
  for (int mi = 0; mi < 4; mi++) {
#pragma unroll
    for (int ni = 0; ni < 4; ni++) {
      int h = hb + mi * 16;
      int n = n0 + wc * 64 + ni * 16 + l15;
      ushort4 o;
      o.x = f2b(acc[mi][ni][0]); o.y = f2b(acc[mi][ni][1]);
      o.z = f2b(acc[mi][ni][2]); o.w = f2b(acc[mi][ni][3]);
      *(ushort4*)&Rt[(long long)img * 65536 + (long long)n * 256 + h] = o;
    }
  }
}

// ---------------------------------------------------------------------------
// MFMA col-DCT + fused top-8 (R2-proven).
// ---------------------------------------------------------------------------
__global__ __launch_bounds__(256) void mfma_coldct_top8(
    const unsigned short* __restrict__ Tb, const unsigned short* __restrict__ Rt,
    float* __restrict__ top8out) {
  __shared__ unsigned short As[128][40];
  __shared__ unsigned short Bs[128][40];
  __shared__ float lists[256 * 8];
  const int tid = threadIdx.x;
  const int m0 = blockIdx.y * 128;
  const int n0 = blockIdx.x * 128;
  const int img = blockIdx.z;
  const int wv = tid >> 6, lane = tid & 63;
  const int wr = wv >> 1, wc = wv & 1;
  const int l15 = lane & 15, kb = lane >> 4;
  const int srow = tid & 127, sseg = tid >> 7;
  const unsigned short* Rb = Rt + (long long)img * 65536;
  f32x4 acc[4][4] = {};

  for (int k0 = 0; k0 < 256; k0 += 32) {
    *(u16x8*)&As[srow][sseg * 8] =
        *(const u16x8*)(Tb + (m0 + srow) * 256 + k0 + sseg * 8);
    *(u16x8*)&Bs[srow][sseg * 8] =
        *(const u16x8*)(Rb + (n0 + srow) * 256 + k0 + sseg * 8);
    __syncthreads();
    bf16x8 a[4], b[4];
#pragma unroll
    for (int mi = 0; mi < 4; mi++)
      a[mi] = *(const bf16x8*)&As[wr * 64 + mi * 16 + l15][kb * 8];
#pragma unroll
    for (int ni = 0; ni < 4; ni++)
      b[ni] = *(const bf16x8*)&Bs[wc * 64 + ni * 16 + l15][kb * 8];
#pragma unroll
    for (int mi = 0; mi < 4; mi++)
#pragma unroll
      for (int ni = 0; ni < 4; ni++)
        acc[mi][ni] = __builtin_amdgcn_mfma_f32_16x16x32_bf16(
            a[mi], b[ni], acc[mi][ni], 0, 0, 0);
    __syncthreads();
  }

  float t[8];
#pragma unroll
  for (int j = 0; j < 8; j++) t[j] = -INFINITY;
#pragma unroll
  for (int mi = 0; mi < 4; mi++)
#pragma unroll
    for (int ni = 0; ni < 4; ni++)
#pragma unroll
      for (int j = 0; j < 4; j++) {
        float v = acc[mi][ni][j];
#pragma unroll
        for (int q = 0; q < 8; q++) {
          if (v > t[q]) { float tmp = t[q]; t[q] = v; v = tmp; }
        }
      }
#pragma unroll
  for (int j = 0; j < 8; j++) lists[tid * 8 + j] = t[j];
  __syncthreads();
  for (int s = 128; s >= 1; s >>= 1) {
    if (tid < s) {
      int ii = 0, jj = 0;
      float out[8];
#pragma unroll
      for (int m = 0; m < 8; m++) {
        float av = lists[tid * 8 + ii];
        float bv = lists[(tid + s) * 8 + jj];
        bool ta = (av >= bv);
        out[m] = ta ? av : bv;
        ii += ta ? 1 : 0;
        jj += ta ? 0 : 1;
      }
#pragma unroll
      for (int m = 0; m < 8; m++) lists[tid * 8 + m] = out[m];
    }
    __syncthreads();
  }
  if (tid < 8) {
    long long idx = ((long long)img * gridDim.y + blockIdx.y) * gridDim.x +
                    blockIdx.x;
    top8out[idx * 8 + tid] = lists[tid];
  }
}

// Merge the 4 per-tile top-8 lists of each image (R2-proven).
__global__ void merge_top8(const float* __restrict__ lists,
                           float* __restrict__ topc) {
  int img = blockIdx.x * 64 + threadIdx.x;
  if (img >= 256) return;
  float t[8];
#pragma unroll
  for (int j = 0; j < 8; j++) t[j] = -INFINITY;
  for (int l = 0; l < 4; l++) {
#pragma unroll
    for (int m = 0; m < 8; m++) {
      float v = lists[(img * 4 + l) * 8 + m];
#pragma unroll
      for (int q = 0; q < 8; q++) {
        if (v > t[q]) { float tmp = t[q]; t[q] = v; v = tmp; }
      }
    }
  }
  int b = img >> 6, c = img & 63;
#pragma unroll
  for (int j = 0; j < 8; j++) topc[b * 512 + c * 8 + j] = t[j];
}

__global__ void mlp_kernel(const float* __restrict__ topc,
                           const float* __restrict__ fc1,
                           const float* __restrict__ fc2,
                           float* __restrict__ wout) {
  __shared__ float hbuf[32];
  int tid = threadIdx.x;
  if (tid < 32) {
    int b = tid >> 3, i = tid & 7;
    float acc = 0.f;
    for (int j = 0; j < 512; j++) acc += topc[b * 512 + j] * fc1[i * 512 + j];
    hbuf[tid] = fmaxf(acc, 0.f);
  }
  __syncthreads();
  int b = tid >> 6, c = tid & 63;
  float acc = 0.f;
#pragma unroll
  for (int i = 0; i < 8; i++) acc += hbuf[b * 8 + i] * fc2[c * 8 + i];
  wout[tid] = 1.0f / (1.0f + expf(-acc));
}

// ---------------------------------------------------------------------------
// out = ip * gate * w   (UNDER TEST).
// ---------------------------------------------------------------------------
__global__ __launch_bounds__(256) void final_scale(
    const float* __restrict__ ip, const float* __restrict__ gateb,
    const float* __restrict__ wfin, float* __restrict__ out) {
  long long i = ((long long)blockIdx.x * 256 + threadIdx.x) * 4;
  int bc = (int)(i >> 16);                 // b*64 + c
  int b = bc >> 6;
  int p = (int)(i & 65535);
  float4 v = *(const float4*)&ip[i];
  float4 g = *(const float4*)&gateb[((long long)b << 16) + p];
  float s = wfin[bc];
  v.x *= g.x * s; v.y *= g.y * s; v.z *= g.z * s; v.w *= g.w * s;
  *(float4*)&out[i] = v;
}

// ---------------------------------------------------------------------------
extern "C" void kernel_launch(void* const* d_in, const int* in_sizes, int n_in,
                              void* d_out, int out_size, void* d_ws,
                              size_t ws_size, hipStream_t stream) {
  (void)in_sizes; (void)n_in; (void)out_size; (void)ws_size;
  const float* ip  = (const float*)d_in[0];
  const float* fc1 = (const float*)d_in[1];
  const float* fc2 = (const float*)d_in[2];
  const float* cw  = (const float*)d_in[3];
  const float* cb  = (const float*)d_in[4];
  float* out = (float*)d_out;
  float* ws = (float*)d_ws;

  // ws layout (floats).
  float* Mc     = ws;                       //   4096
  unsigned short* Tb = (unsigned short*)(ws + 8192);   // 65536 u16
  float* gateb  = ws + 139264;              // 262144
  float* wfin   = ws + 401408;              //    256
  float* topc   = ws + 401664;              //   2048
  float* listsb = ws + 403712;              //   8192
  float* ca     = ws + 1048576;             // 16777216 (ca; Rt aliases later)
  float* ct8    = ws + 1048576 + 16777216;  //  2097152

  const long long CHW = (long long)NCH * HW;

  gen_tables<<<256, 256, 0, stream>>>(Mc, Tb);

  // ca = Mc @ ip   (R2-proven)
  gemm64<<<dim3(1024, 1, 4), 256, 0, stream>>>(
      Mc, 64, 0, ip, HW, CHW, ca, HW, CHW, 64, nullptr, 0);

  top8_chan<<<1024, 256, 0, stream>>>(ca, ct8);
  conv_gate<<<1024, 256, 0, stream>>>(ct8, cw, cb, gateb);

  // Rt = row-DCT of (ip*gate), transposed per image (ca buffer is dead now)
  unsigned short* Rt = (unsigned short*)ca;
  mfma_rowdct<<<dim3(2, 512), 256, 0, stream>>>(ip, gateb, Tb, Rt);

  // col-DCT + fused top-8
  mfma_coldct_top8<<<dim3(2, 2, 256), 256, 0, stream>>>(Tb, Rt, listsb);

  merge_top8<<<4, 64, 0, stream>>>(listsb, topc);
  mlp_kernel<<<1, 256, 0, stream>>>(topc, fc1, fc2, wfin);

  // out = ip * gate * w
  final_scale<<<16384, 256, 0, stream>>>(ip, gateb, wfin, out);
}

// Round 7
// 282.336 us; speedup vs baseline: 1.9209x; 1.0502x over previous
//
#include <hip/hip_runtime.h>
#include <hip/hip_bf16.h>
#include <math.h>

#define HW 65536
#define NCH 64
#define NB 4

typedef __attribute__((ext_vector_type(8))) short bf16x8;
typedef __attribute__((ext_vector_type(4))) float f32x4;
typedef __attribute__((ext_vector_type(8))) unsigned short u16x8;

__device__ inline unsigned short f2b(float f) {
  __hip_bfloat16 h = __float2bfloat16(f);
  return *(unsigned short*)&h;
}

// Merge two sorted-descending 8-lists -> top-8 of the 16, sorted (in A).
// M[i] = max(A[i], B[i], max_{j<i} min(A[j], B[i-1-j])).  Static indexing only.
__device__ inline void merge8(float A[8], const float B[8]) {
  float M[8];
#pragma unroll
  for (int i = 0; i < 8; i++) {
    float m = fmaxf(A[i], B[i]);
#pragma unroll
    for (int j = 0; j < i; j++) m = fmaxf(m, fminf(A[j], B[i - 1 - j]));
    M[i] = m;
  }
#pragma unroll
  for (int i = 0; i < 8; i++) A[i] = M[i];
}

// ---------------------------------------------------------------------------
// Tables. Mc[k][c] = cos(pi*k*(2c+1)/128)/64 (channel DCT-II, fp32).
// Tb[n][k] = bf16(cos(pi*n*(2k+1)/512)/256)  (spatial DCT table).
// x = idct_chan(dct_chan(ip)*g) == ip*g exactly (gate channel-constant,
// idct inverts dct) -- R6-proven.
// ---------------------------------------------------------------------------
__global__ void gen_tables(float* __restrict__ Mc,
                           unsigned short* __restrict__ Tb) {
  int i = blockIdx.x * 256 + threadIdx.x;   // 0 .. 65535
  const double PI = 3.14159265358979323846;
  if (i < 4096) {
    int k = i >> 6, c = i & 63;
    Mc[i] = (float)(cos(PI * (double)(k * (2 * c + 1)) / 128.0) / 64.0);
  }
  {
    int n = i >> 8, k = i & 255;
    float v = (float)(cos(PI * (double)(n * (2 * k + 1)) / 512.0) / 256.0);
    Tb[i] = f2b(v);
  }
}

// ---------------------------------------------------------------------------
// Channel DCT GEMM + fused per-pixel top-8.  ca is never materialized.
// Block: 64 ch x 64 pixels, K=64 (R2-proven gemm64 core).  Epilogue:
// transpose acc to LDS pixel-major, 4-way partial top-8, static merge.
// Output ct[b][j][p] identical to the old top8_chan.
// ---------------------------------------------------------------------------
__global__ __launch_bounds__(256) void chan_gemm_top8(
    const float* __restrict__ ip, const float* __restrict__ Mc,
    float* __restrict__ ct) {
  __shared__ float As[16][68];
  __shared__ float Bs[16][68];
  __shared__ float T[64][69];      // [pixel][channel], pad 69 (5-coprime-32)
  __shared__ float lists[64][33];  // 4 sorted-8 partials per pixel
  const int tid = threadIdx.x;
  const int tx = tid & 15, ty = tid >> 4;
  const int bn = blockIdx.x, bz = blockIdx.z;
  const float* Bp = ip + (long long)bz * NCH * HW;
  const long long n0 = (long long)bn * 64;
  const int bcol = tid & 63;
  const int brow = tid >> 6;
  const int acol = tid & 15;
  const int arow = tid >> 4;
  float acc[4][4] = {{0.f}};

  for (int k0 = 0; k0 < 64; k0 += 16) {
#pragma unroll
    for (int i = 0; i < 4; i++) {
      int r = arow + 16 * i;
      As[acol][r] = Mc[r * 64 + (k0 + acol)];
    }
#pragma unroll
    for (int i = 0; i < 4; i++) {
      int r = brow + 4 * i;
      Bs[r][bcol] = Bp[(long long)(k0 + r) * HW + n0 + bcol];
    }
    __syncthreads();
#pragma unroll
    for (int kk = 0; kk < 16; kk++) {
      float4 a4 = *(const float4*)&As[kk][ty * 4];
      float4 b4 = *(const float4*)&Bs[kk][tx * 4];
      float a[4] = {a4.x, a4.y, a4.z, a4.w};
      float b[4] = {b4.x, b4.y, b4.z, b4.w};
#pragma unroll
      for (int i = 0; i < 4; i++)
#pragma unroll
        for (int j = 0; j < 4; j++) acc[i][j] = fmaf(a[i], b[j], acc[i][j]);
    }
    __syncthreads();
  }

  // acc[i][j] = ca[ch ty*4+i][pix tx*4+j]  -> T[pix][ch]
#pragma unroll
  for (int j = 0; j < 4; j++) {
    int pix = tx * 4 + j;
#pragma unroll
    for (int i = 0; i < 4; i++) T[pix][ty * 4 + i] = acc[i][j];
  }
  __syncthreads();
  {  // partial top-8: thread (pix = tid&63, q = tid>>6) handles 16 channels
    int pix = tid & 63, q = tid >> 6;
    float t8[8];
#pragma unroll
    for (int j = 0; j < 8; j++) t8[j] = -INFINITY;
#pragma unroll
    for (int c = 0; c < 16; c++) {
      float v = T[pix][q * 16 + c];
#pragma unroll
      for (int s = 0; s < 8; s++) {
        if (v > t8[s]) { float tmp = t8[s]; t8[s] = v; v = tmp; }
      }
    }
#pragma unroll
    for (int j = 0; j < 8; j++) lists[pix][q * 8 + j] = t8[j];
  }
  __syncthreads();
  if (tid < 64) {  // final merge of 4 sorted-8 lists per pixel
    float A8[8];
#pragma unroll
    for (int j = 0; j < 8; j++) A8[j] = lists[tid][j];
#pragma unroll
    for (int q = 1; q < 4; q++) {
      float B8[8];
#pragma unroll
      for (int j = 0; j < 8; j++) B8[j] = lists[tid][q * 8 + j];
      merge8(A8, B8);
    }
    float* dst = ct + (long long)bz * 8 * HW + n0 + tid;
#pragma unroll
    for (int j = 0; j < 8; j++) dst[(long long)j * HW] = A8[j];
  }
}

// ---------------------------------------------------------------------------
// 3x3 conv (8 in-ch -> 1) SAME + sigmoid -> gate (R2-proven).
// ---------------------------------------------------------------------------
__global__ __launch_bounds__(256) void conv_gate(const float* __restrict__ ct,
                                                 const float* __restrict__ cw,
                                                 const float* __restrict__ cbias,
                                                 float* __restrict__ gate) {
  int gidx = blockIdx.x * 256 + threadIdx.x;
  int b = gidx >> 16, p = gidx & 65535;
  int h = p >> 8, w = p & 255;
  float acc = cbias[0];
#pragma unroll
  for (int j = 0; j < 8; j++) {
    const float* base = ct + ((long long)b * 8 + j) * HW;
#pragma unroll
    for (int dy = 0; dy < 3; dy++) {
      int y = h + dy - 1;
      if ((unsigned)y < 256u) {
#pragma unroll
        for (int dx = 0; dx < 3; dx++) {
          int x = w + dx - 1;
          if ((unsigned)x < 256u)
            acc += base[y * 256 + x] * cw[j * 9 + dy * 3 + dx];
        }
      }
    }
  }
  gate[gidx] = 1.0f / (1.0f + expf(-acc));
}

// ---------------------------------------------------------------------------
// MFMA row-DCT, x = ip*gate on the fly (R6-proven math), now with
// register-prefetched staging: next k-tile's global loads issue right after
// the barrier and fly during ds_read+MFMA.
// ---------------------------------------------------------------------------
__global__ __launch_bounds__(256) void mfma_rowdct(
    const float* __restrict__ ip, const float* __restrict__ gateb,
    const unsigned short* __restrict__ Tb, unsigned short* __restrict__ Rt) {
  __shared__ unsigned short As[128][40];
  __shared__ unsigned short Bs[128][40];
  const int tid = threadIdx.x;
  const int m0 = blockIdx.y * 128;         // global row (b*64+c)*256 + h
  const int n0 = blockIdx.x * 128;         // wfreq
  const int wv = tid >> 6, lane = tid & 63;
  const int wr = wv >> 1, wc = wv & 1;
  const int l15 = lane & 15, kb = lane >> 4;
  const int srow = tid & 127, sseg = tid >> 7;
  const int r = m0 + srow;
  const int hh = r & 255;
  const int bb = r >> 14;
  const float* p  = ip + (long long)r * 256 + sseg * 8;
  const float* gp = gateb + ((long long)bb << 16) + (hh << 8) + sseg * 8;
  const unsigned short* tp = Tb + (n0 + srow) * 256 + sseg * 8;
  f32x4 acc[4][4] = {};

  float4 v0 = *(const float4*)p,  v1 = *(const float4*)(p + 4);
  float4 g0 = *(const float4*)gp, g1 = *(const float4*)(gp + 4);
  u16x8 rT = *(const u16x8*)tp;

  for (int it = 0; it < 8; ++it) {
    u16x8 w;
    w[0] = f2b(v0.x * g0.x); w[1] = f2b(v0.y * g0.y);
    w[2] = f2b(v0.z * g0.z); w[3] = f2b(v0.w * g0.w);
    w[4] = f2b(v1.x * g1.x); w[5] = f2b(v1.y * g1.y);
    w[6] = f2b(v1.z * g1.z); w[7] = f2b(v1.w * g1.w);
    *(u16x8*)&As[srow][sseg * 8] = w;
    *(u16x8*)&Bs[srow][sseg * 8] = rT;
    __syncthreads();
    if (it < 7) {  // prefetch next k-tile (in flight during MFMA phase)
      int o = (it + 1) * 32;
      v0 = *(const float4*)(p + o);  v1 = *(const float4*)(p + o + 4);
      g0 = *(const float4*)(gp + o); g1 = *(const float4*)(gp + o + 4);
      rT = *(const u16x8*)(tp + o);
    }
    bf16x8 a[4], b[4];
#pragma unroll
    for (int mi = 0; mi < 4; mi++)
      a[mi] = *(const bf16x8*)&As[wr * 64 + mi * 16 + l15][kb * 8];
#pragma unroll
    for (int ni = 0; ni < 4; ni++)
      b[ni] = *(const bf16x8*)&Bs[wc * 64 + ni * 16 + l15][kb * 8];
#pragma unroll
    for (int mi = 0; mi < 4; mi++)
#pragma unroll
      for (int ni = 0; ni < 4; ni++)
        acc[mi][ni] = __builtin_amdgcn_mfma_f32_16x16x32_bf16(
            a[mi], b[ni], acc[mi][ni], 0, 0, 0);
    __syncthreads();
  }

  const int img = m0 >> 8;
  const int hb = (m0 & 255) + wr * 64 + kb * 4;
#pragma unroll
  for (int mi = 0; mi < 4; mi++) {
#pragma unroll
    for (int ni = 0; ni < 4; ni++) {
      int h = hb + mi * 16;
      int n = n0 + wc * 64 + ni * 16 + l15;
      ushort4 o;
      o.x = f2b(acc[mi][ni][0]); o.y = f2b(acc[mi][ni][1]);
      o.z = f2b(acc[mi][ni][2]); o.w = f2b(acc[mi][ni][3]);
      *(ushort4*)&Rt[(long long)img * 65536 + (long long)n * 256 + h] = o;
    }
  }
}

// ---------------------------------------------------------------------------
// MFMA col-DCT + fused top-8.  Register-prefetched staging; shfl-butterfly
// top-8 reduction with static merge8 (no LDS merge tree, 1 barrier).
// ---------------------------------------------------------------------------
__global__ __launch_bounds__(256) void mfma_coldct_top8(
    const unsigned short* __restrict__ Tb, const unsigned short* __restrict__ Rt,
    float* __restrict__ top8out) {
  __shared__ unsigned short As[128][40];
  __shared__ unsigned short Bs[128][40];
  __shared__ float wl[4][8];
  const int tid = threadIdx.x;
  const int m0 = blockIdx.y * 128;
  const int n0 = blockIdx.x * 128;
  const int img = blockIdx.z;
  const int wv = tid >> 6, lane = tid & 63;
  const int wr = wv >> 1, wc = wv & 1;
  const int l15 = lane & 15, kb = lane >> 4;
  const int srow = tid & 127, sseg = tid >> 7;
  const unsigned short* Ap = Tb + (m0 + srow) * 256 + sseg * 8;
  const unsigned short* Bp = Rt + (long long)img * 65536 + (n0 + srow) * 256 +
                             sseg * 8;
  f32x4 acc[4][4] = {};

  u16x8 rA = *(const u16x8*)Ap;
  u16x8 rB = *(const u16x8*)Bp;

  for (int it = 0; it < 8; ++it) {
    *(u16x8*)&As[srow][sseg * 8] = rA;
    *(u16x8*)&Bs[srow][sseg * 8] = rB;
    __syncthreads();
    if (it < 7) {
      rA = *(const u16x8*)(Ap + (it + 1) * 32);
      rB = *(const u16x8*)(Bp + (it + 1) * 32);
    }
    bf16x8 a[4], b[4];
#pragma unroll
    for (int mi = 0; mi < 4; mi++)
      a[mi] = *(const bf16x8*)&As[wr * 64 + mi * 16 + l15][kb * 8];
#pragma unroll
    for (int ni = 0; ni < 4; ni++)
      b[ni] = *(const bf16x8*)&Bs[wc * 64 + ni * 16 + l15][kb * 8];
#pragma unroll
    for (int mi = 0; mi < 4; mi++)
#pragma unroll
      for (int ni = 0; ni < 4; ni++)
        acc[mi][ni] = __builtin_amdgcn_mfma_f32_16x16x32_bf16(
            a[mi], b[ni], acc[mi][ni], 0, 0, 0);
    __syncthreads();
  }

  // per-thread sorted top-8 of its 64 acc values
  float t8[8];
#pragma unroll
  for (int j = 0; j < 8; j++) t8[j] = -INFINITY;
#pragma unroll
  for (int mi = 0; mi < 4; mi++)
#pragma unroll
    for (int ni = 0; ni < 4; ni++)
#pragma unroll
      for (int j = 0; j < 4; j++) {
        float v = acc[mi][ni][j];
#pragma unroll
        for (int q = 0; q < 8; q++) {
          if (v > t8[q]) { float tmp = t8[q]; t8[q] = v; v = tmp; }
        }
      }
  // wave-level butterfly merge (all lanes converge to wave top-8)
#pragma unroll
  for (int st = 1; st < 64; st <<= 1) {
    float B8[8];
#pragma unroll
    for (int j = 0; j < 8; j++) B8[j] = __shfl_xor(t8[j], st, 64);
    merge8(t8, B8);
  }
  if (lane == 0) {
#pragma unroll
    for (int j = 0; j < 8; j++) wl[wv][j] = t8[j];
  }
  __syncthreads();
  if (tid == 0) {  // merge the 4 wave lists (t8 already == wave 0's list)
#pragma unroll
    for (int w = 1; w < 4; w++) {
      float B8[8];
#pragma unroll
      for (int j = 0; j < 8; j++) B8[j] = wl[w][j];
      merge8(t8, B8);
    }
    long long idx = ((long long)img * gridDim.y + blockIdx.y) * gridDim.x +
                    blockIdx.x;
#pragma unroll
    for (int j = 0; j < 8; j++) top8out[idx * 8 + j] = t8[j];
  }
}

// Merge the 4 per-tile top-8 lists of each image (R2-proven).
__global__ void merge_top8(const float* __restrict__ lists,
                           float* __restrict__ topc) {
  int img = blockIdx.x * 64 + threadIdx.x;
  if (img >= 256) return;
  float t[8];
#pragma unroll
  for (int j = 0; j < 8; j++) t[j] = -INFINITY;
  for (int l = 0; l < 4; l++) {
#pragma unroll
    for (int m = 0; m < 8; m++) {
      float v = lists[(img * 4 + l) * 8 + m];
#pragma unroll
      for (int q = 0; q < 8; q++) {
        if (v > t[q]) { float tmp = t[q]; t[q] = v; v = tmp; }
      }
    }
  }
  int b = img >> 6, c = img & 63;
#pragma unroll
  for (int j = 0; j < 8; j++) topc[b * 512 + c * 8 + j] = t[j];
}

__global__ void mlp_kernel(const float* __restrict__ topc,
                           const float* __restrict__ fc1,
                           const float* __restrict__ fc2,
                           float* __restrict__ wout) {
  __shared__ float hbuf[32];
  int tid = threadIdx.x;
  if (tid < 32) {
    int b = tid >> 3, i = tid & 7;
    float acc = 0.f;
    for (int j = 0; j < 512; j++) acc += topc[b * 512 + j] * fc1[i * 512 + j];
    hbuf[tid] = fmaxf(acc, 0.f);
  }
  __syncthreads();
  int b = tid >> 6, c = tid & 63;
  float acc = 0.f;
#pragma unroll
  for (int i = 0; i < 8; i++) acc += hbuf[b * 8 + i] * fc2[c * 8 + i];
  wout[tid] = 1.0f / (1.0f + expf(-acc));
}

// ---------------------------------------------------------------------------
// out = ip * gate * w   (R6-proven).
// ---------------------------------------------------------------------------
__global__ __launch_bounds__(256) void final_scale(
    const float* __restrict__ ip, const float* __restrict__ gateb,
    const float* __restrict__ wfin, float* __restrict__ out) {
  long long i = ((long long)blockIdx.x * 256 + threadIdx.x) * 4;
  int bc = (int)(i >> 16);                 // b*64 + c
  int b = bc >> 6;
  int p = (int)(i & 65535);
  float4 v = *(const float4*)&ip[i];
  float4 g = *(const float4*)&gateb[((long long)b << 16) + p];
  float s = wfin[bc];
  v.x *= g.x * s; v.y *= g.y * s; v.z *= g.z * s; v.w *= g.w * s;
  *(float4*)&out[i] = v;
}

// ---------------------------------------------------------------------------
extern "C" void kernel_launch(void* const* d_in, const int* in_sizes, int n_in,
                              void* d_out, int out_size, void* d_ws,
                              size_t ws_size, hipStream_t stream) {
  (void)in_sizes; (void)n_in; (void)out_size; (void)ws_size;
  const float* ip  = (const float*)d_in[0];
  const float* fc1 = (const float*)d_in[1];
  const float* fc2 = (const float*)d_in[2];
  const float* cw  = (const float*)d_in[3];
  const float* cb  = (const float*)d_in[4];
  float* out = (float*)d_out;
  float* ws = (float*)d_ws;

  // ws layout (floats).
  float* Mc     = ws;                       //   4096
  unsigned short* Tb = (unsigned short*)(ws + 8192);   // 65536 u16
  float* gateb  = ws + 139264;              // 262144
  float* wfin   = ws + 401408;              //    256
  float* topc   = ws + 401664;              //   2048
  float* listsb = ws + 403712;              //   8192
  float* big    = ws + 1048576;             // Rt: 256*65536 u16
  float* ct8    = ws + 1048576 + 16777216;  //  2097152

  gen_tables<<<256, 256, 0, stream>>>(Mc, Tb);

  // channel DCT + fused per-pixel top-8 (ca never materialized)
  chan_gemm_top8<<<dim3(1024, 1, 4), 256, 0, stream>>>(ip, Mc, ct8);
  conv_gate<<<1024, 256, 0, stream>>>(ct8, cw, cb, gateb);

  // Rt = row-DCT of (ip*gate), transposed per image (bf16)
  unsigned short* Rt = (unsigned short*)big;
  mfma_rowdct<<<dim3(2, 512), 256, 0, stream>>>(ip, gateb, Tb, Rt);

  // col-DCT + fused top-8
  mfma_coldct_top8<<<dim3(2, 2, 256), 256, 0, stream>>>(Tb, Rt, listsb);

  merge_top8<<<4, 64, 0, stream>>>(listsb, topc);
  mlp_kernel<<<1, 256, 0, stream>>>(topc, fc1, fc2, wfin);

  // out = ip * gate * w
  final_scale<<<16384, 256, 0, stream>>>(ip, gateb, wfin, out);
}